// Round 13
// baseline (2746.194 us; speedup 1.0000x reference)
//
#include <hip/hip_runtime.h>

typedef unsigned short u16;
typedef unsigned int u32;
typedef unsigned long long u64;
typedef __bf16 bfx8 __attribute__((ext_vector_type(8)));
typedef float f32x4 __attribute__((ext_vector_type(4)));

constexpr int BB = 64;     // batch
constexpr int TT = 64;     // time
constexpr int EE = 2048;   // x feature
constexpr int DD = 4096;   // deter
constexpr int GG = 8;      // groups
constexpr int H3 = 3 * DD;       // 12288
constexpr int CH = H3 / GG;      // 1536
constexpr float EPSf = 1e-4f;

static __device__ __forceinline__ u16 f2bf(float f) {
  u32 u = __builtin_bit_cast(u32, f);
  u32 r = (u + 0x7fffu + ((u >> 16) & 1u)) >> 16;
  return (u16)r;
}
static __device__ __forceinline__ float bf2f(u16 h) {
  return __builtin_bit_cast(float, (u32)h << 16);
}

// ---- device-scope (agent) accessors: coherent at L3 (round-8 validated) ----
static __device__ __forceinline__ uint2 ld_dev2(const void* p) {
  u64 v = __hip_atomic_load((const u64*)p, __ATOMIC_RELAXED, __HIP_MEMORY_SCOPE_AGENT);
  uint2 r; r.x = (u32)v; r.y = (u32)(v >> 32);
  return r;
}
static __device__ __forceinline__ void st_dev2(void* p, u32 lo, u32 hi) {
  u64 x = (u64)lo | ((u64)hi << 32);
  __hip_atomic_store((u64*)p, x, __ATOMIC_RELAXED, __HIP_MEMORY_SCOPE_AGENT);
}
static __device__ __forceinline__ float ld_devf(const float* p) {
  return __hip_atomic_load(p, __ATOMIC_RELAXED, __HIP_MEMORY_SCOPE_AGENT);
}
static __device__ __forceinline__ void st_devf(float* p, float v) {
  __hip_atomic_store(p, v, __ATOMIC_RELAXED, __HIP_MEMORY_SCOPE_AGENT);
}
static __device__ __forceinline__ float2 u2f2(uint2 v) {
  float2 r;
  r.x = __builtin_bit_cast(float, v.x);
  r.y = __builtin_bit_cast(float, v.y);
  return r;
}

// Fence-free intra-dispatch device barrier (round-8 validated). All WGs
// co-resident (grid=256 at 1 WG/CU). Mutable cross-WG data must use sc1.
static __device__ __forceinline__ void gbar(int* cnt, int target) {
  __syncthreads();
  if (threadIdx.x == 0) {
    __hip_atomic_fetch_add(cnt, 1, __ATOMIC_RELAXED, __HIP_MEMORY_SCOPE_AGENT);
    while (__hip_atomic_load(cnt, __ATOMIC_RELAXED, __HIP_MEMORY_SCOPE_AGENT) < target)
      __builtin_amdgcn_s_sleep(2);
  }
  __syncthreads();
  asm volatile("" ::: "memory");
}

// async global->LDS, 16B per lane
#define GLOAD_LDS16(gp, lp)                                                    \
  __builtin_amdgcn_global_load_lds(                                           \
      (const __attribute__((address_space(1))) void*)(gp),                    \
      (__attribute__((address_space(3))) void*)(lp), 16, 0, 0)

// ---------------- prepass kernels ----------------

__global__ void __launch_bounds__(256) k_f2b(const float* __restrict__ in,
                                             u16* __restrict__ out, int n4) {
  int i = blockIdx.x * 256 + threadIdx.x;
  int stride = gridDim.x * 256;
  for (; i < n4; i += stride) {
    float4 v = ((const float4*)in)[i];
    uint2 o;
    o.x = (u32)f2bf(v.x) | ((u32)f2bf(v.y) << 16);
    o.y = (u32)f2bf(v.z) | ((u32)f2bf(v.w) << 16);
    ((uint2*)out)[i] = o;
  }
}

__global__ void __launch_bounds__(256) k_initdet(const float* __restrict__ d0,
                                                 float* __restrict__ dF,
                                                 u16* __restrict__ dB, int n4) {
  int i = blockIdx.x * 256 + threadIdx.x;
  if (i < n4) {
    float4 v = ((const float4*)d0)[i];
    ((float4*)dF)[i] = v;
    uint2 o;
    o.x = (u32)f2bf(v.x) | ((u32)f2bf(v.y) << 16);
    o.y = (u32)f2bf(v.z) | ((u32)f2bf(v.w) << 16);
    ((uint2*)dB)[i] = o;
  }
}

__global__ void __launch_bounds__(256) k_zero(int* __restrict__ p, int n) {
  int i = blockIdx.x * 256 + threadIdx.x;
  if (i < n) p[i] = 0;
}

// in [R][C] f32 -> out [C][R] bf16  (batched over blockIdx.z)
__global__ void __launch_bounds__(256) k_transpose_f2b(const float* __restrict__ in,
                                                       u16* __restrict__ out,
                                                       int R, int C) {
  __shared__ float tile[32][33];
  size_t base = (size_t)blockIdx.z * R * C;
  in += base; out += base;
  int tx = threadIdx.x & 31, ty = threadIdx.x >> 5;
  int r0 = blockIdx.y * 32, c0 = blockIdx.x * 32;
#pragma unroll
  for (int i = 0; i < 4; i++) {
    int rr = ty * 4 + i;
    tile[rr][tx] = in[(size_t)(r0 + rr) * C + (c0 + tx)];
  }
  __syncthreads();
#pragma unroll
  for (int i = 0; i < 4; i++) {
    int cc = ty * 4 + i;
    out[(size_t)(c0 + cc) * R + (r0 + tx)] = f2bf(tile[tx][cc]);
  }
}

// ---------------- P1: Xproj = x @ W2 + b_in -> bf16 (round-11 proven, ~105us) ----------------

__global__ void __launch_bounds__(256) k_p1(const u16* __restrict__ A,  // [4096][2048]
                                            const u16* __restrict__ B,  // [4096][6144]
                                            const float* __restrict__ bias,
                                            u16* __restrict__ C) {      // [4096][4096] bf16
  __shared__ u16 As[128 * 64];
  __shared__ u16 Bs[128 * 64];
  const int tid = threadIdx.x;
  const int m0 = blockIdx.y * 128, n0 = blockIdx.x * 128;
  const int w = tid >> 6, lane = tid & 63;
  const int wr = w >> 1, wc = w & 1;
  const int lr = lane & 15, lk = (lane >> 4) * 8;
  const int lrow = lane >> 3;
  const int lcol = (lane & 7) * 8;
  const u16* gA[4];
  const u16* gB[4];
  u16* lA[4];
  u16* lB[4];
#pragma unroll
  for (int i = 0; i < 4; i++) {
    const int chunk = w * 4 + i;
    const int row = chunk * 8 + lrow;
    gA[i] = A + (size_t)(m0 + row) * EE + lcol;
    gB[i] = B + (size_t)(n0 + row) * (DD + EE) + lcol;
    lA[i] = &As[chunk * 512];
    lB[i] = &Bs[chunk * 512];
  }

  f32x4 acc[4][4] = {};

  for (int kt = 0; kt < EE; kt += 64) {
#pragma unroll
    for (int i = 0; i < 4; i++) {
      GLOAD_LDS16(gA[i] + kt, lA[i]);
      GLOAD_LDS16(gB[i] + kt, lB[i]);
    }
    __syncthreads();
#pragma unroll
    for (int kk = 0; kk < 64; kk += 32) {
      bfx8 av[4], bv[4];
#pragma unroll
      for (int mi = 0; mi < 4; mi++)
        av[mi] = *(const bfx8*)&As[(wr * 64 + mi * 16 + lr) * 64 + kk + lk];
#pragma unroll
      for (int ni = 0; ni < 4; ni++)
        bv[ni] = *(const bfx8*)&Bs[(wc * 64 + ni * 16 + lr) * 64 + kk + lk];
#pragma unroll
      for (int mi = 0; mi < 4; mi++)
#pragma unroll
        for (int ni = 0; ni < 4; ni++)
          acc[mi][ni] = __builtin_amdgcn_mfma_f32_16x16x32_bf16(av[mi], bv[ni], acc[mi][ni], 0, 0, 0);
    }
    __syncthreads();
  }

  const int rq = (lane >> 4) * 4;
#pragma unroll
  for (int mi = 0; mi < 4; mi++) {
#pragma unroll
    for (int ni = 0; ni < 4; ni++) {
      const int n = n0 + wc * 64 + ni * 16 + lr;
      const float bias_v = bias[n];
#pragma unroll
      for (int r = 0; r < 4; r++) {
        const int m = m0 + wr * 64 + mi * 16 + rq + r;
        C[(size_t)m * DD + n] = f2bf(acc[mi][ni][r] + bias_v);
      }
    }
  }
}

// ---------------- fused per-step kernel: 256 WGs x 512 thr, 3 internal gbars ----------------
// Phase A: round-11 kA body (best measured). Phase B/C: round-9 512-thr bodies.
// Phase D: round-9 gates re-indexed to 256 WGs. Intra-dispatch cross-WG data
// (part, ybf, zbuf, zsq) via sc1; dF/dB/out cross dispatch boundaries -> plain.

constexpr int LSA = 136;                 // 128 + 8 pad
constexpr int ABUF = 64 * LSA;           // 8704 u16
constexpr int LSC2 = 72;
constexpr int CBUF = 64 * LSC2;          // 4608 u16

__global__ void __launch_bounds__(512) kStep(const u16* __restrict__ dB,
                                             const u16* __restrict__ WT,
                                             const u16* __restrict__ Xproj,
                                             const float* __restrict__ scale_in,
                                             const u16* __restrict__ WbT,
                                             const float* __restrict__ b_blk,
                                             const float* __restrict__ sblk,
                                             float* __restrict__ part,   // sc1 [4][64][4096]
                                             u16* __restrict__ ybf,      // sc1 [64][4096]
                                             float* __restrict__ zbuf,   // sc1 [64][12288]
                                             float* __restrict__ zsq,    // sc1 [192][128]
                                             float* __restrict__ dF,
                                             u16* __restrict__ dBout,
                                             float* __restrict__ out,
                                             int t, int* bars) {
  __shared__ __align__(16) u16 U[4 * ABUF];   // 69.6 KB, unioned across phases
  __shared__ float sred[8];
  const int wg = blockIdx.x, tid = threadIdx.x;
  const int w = tid >> 6, lane = tid & 63;
  const int lr = lane & 15, lk = (lane >> 4) * 8, rq = (lane >> 4) * 4;

  // ---------- Phase A (round-11 kA): part[kc] = dB @ W1 slice ----------
  {
    u16* As = U;
    u16* Bs = U + 2 * ABUF;
    const int n0 = (wg & 63) * 64;
    const int k0 = (wg >> 6) * 1024;
    const int wr = w >> 1, wc = w & 1;
    const int r0s = tid >> 4, s0 = (tid & 15) * 8;   // rows 0..31
    const int r1s = r0s + 32;                         // rows 32..63
    const u16* Ag0 = dB + (size_t)r0s * DD + k0 + s0;
    const u16* Ag1 = dB + (size_t)r1s * DD + k0 + s0;
    const u16* Bg0 = WT + (size_t)(n0 + r0s) * (DD + EE) + k0 + s0;
    const u16* Bg1 = WT + (size_t)(n0 + r1s) * (DD + EE) + k0 + s0;
    const int d0 = r0s * LSA + s0, d1 = r1s * LSA + s0;

    f32x4 acc[2] = {};
    uint4 ra0 = *(const uint4*)(Ag0);
    uint4 ra1 = *(const uint4*)(Ag1);
    uint4 rb0 = *(const uint4*)(Bg0);
    uint4 rb1 = *(const uint4*)(Bg1);

    for (int kt = 0; kt < 8; ++kt) {
      const int p = kt & 1;
      u16* ab = As + p * ABUF;
      u16* bb = Bs + p * ABUF;
      *(uint4*)&ab[d0] = ra0;
      *(uint4*)&ab[d1] = ra1;
      *(uint4*)&bb[d0] = rb0;
      *(uint4*)&bb[d1] = rb1;
      __syncthreads();
      if (kt < 7) {
        const int ko = (kt + 1) * 128;
        ra0 = *(const uint4*)(Ag0 + ko);
        ra1 = *(const uint4*)(Ag1 + ko);
        rb0 = *(const uint4*)(Bg0 + ko);
        rb1 = *(const uint4*)(Bg1 + ko);
      }
#pragma unroll
      for (int kk = 0; kk < 128; kk += 32) {
        bfx8 av = *(const bfx8*)&ab[(wr * 16 + lr) * LSA + kk + lk];
#pragma unroll
        for (int ni = 0; ni < 2; ni++) {
          bfx8 bv = *(const bfx8*)&bb[(wc * 32 + ni * 16 + lr) * LSA + kk + lk];
          acc[ni] = __builtin_amdgcn_mfma_f32_16x16x32_bf16(av, bv, acc[ni], 0, 0, 0);
        }
      }
    }

    float* Pp = part + (size_t)(wg >> 6) * BB * DD;
#pragma unroll
    for (int ni = 0; ni < 2; ni++)
#pragma unroll
      for (int r = 0; r < 4; r++)
        st_devf(&Pp[(size_t)(wr * 16 + rq + r) * DD + n0 + wc * 32 + ni * 16 + lr],
                acc[ni][r]);
  }

  gbar(bars + 0, 256);

  // ---------- Phase B (round-9 body): y = silu(rms(sum part + Xproj_t)*scale) ----------
  if (wg < BB) {
    const int b = wg;
    const u16* xp = Xproj + ((size_t)b * TT + t) * DD + tid * 8;
    const float* pb = part + (size_t)b * DD + tid * 8;
    float v[8];
    uint4 x0 = *(const uint4*)(xp);
#pragma unroll
    for (int j = 0; j < 8; j++) v[j] = bf2f(((const u16*)&x0)[j]);
#pragma unroll
    for (int kc = 0; kc < 4; kc++) {
      const float* p = pb + (size_t)kc * BB * DD;
#pragma unroll
      for (int j2 = 0; j2 < 4; j2++) {
        float2 q = u2f2(ld_dev2(p + j2 * 2));
        v[j2 * 2] += q.x;
        v[j2 * 2 + 1] += q.y;
      }
    }
    float ss = 0.f;
#pragma unroll
    for (int j = 0; j < 8; j++) ss += v[j] * v[j];
#pragma unroll
    for (int o = 32; o > 0; o >>= 1) ss += __shfl_down(ss, o);
    if (lane == 0) sred[w] = ss;
    __syncthreads();
    float tot = 0.f;
#pragma unroll
    for (int i = 0; i < 8; i++) tot += sred[i];
    const float r = rsqrtf(tot / (float)DD + EPSf);
    const float* sc = scale_in + tid * 8;
    u32 pk[4];
#pragma unroll
    for (int j = 0; j < 4; j++) {
      float a = v[2 * j] * r * sc[2 * j];
      float bq = v[2 * j + 1] * r * sc[2 * j + 1];
      a = a / (1.f + __expf(-a));
      bq = bq / (1.f + __expf(-bq));
      pk[j] = (u32)f2bf(a) | ((u32)f2bf(bq) << 16);
    }
    u16* yb = ybf + (size_t)b * DD + tid * 8;
    st_dev2(yb, pk[0], pk[1]);
    st_dev2(yb + 4, pk[2], pk[3]);
  }

  gbar(bars + 1, 256);

  // ---------- Phase C (round-9 body): z = blockdiag(y @ Wblk) + b_blk; zsq partials ----------
  if (wg < 192) {
    u16* As = U;
    u16* Bs = U + 2 * CBUF;
    const int n0g = wg * 64;
    const int g = wg / 24, nl = n0g - g * CH;
    const int wr = w >> 1, wc = w & 1;
    const int srow = tid >> 3, sc = (tid & 7) * 8;
    const u16* Arow = ybf + (size_t)srow * DD + g * 512 + sc;        // sc1
    const u16* Brow = WbT + ((size_t)g * CH + nl + srow) * 512 + sc; // plain
    const int dA = srow * LSC2 + sc;
    u16* A0 = As;        u16* B0 = Bs;
    u16* A1 = As + CBUF; u16* B1 = Bs + CBUF;

    f32x4 acc[2] = {};
    uint2 ea0 = ld_dev2(Arow),      ea1 = ld_dev2(Arow + 4);
    uint4 eb  = *(const uint4*)(Brow);
    uint2 oa0 = ld_dev2(Arow + 64), oa1 = ld_dev2(Arow + 68);
    uint4 ob  = *(const uint4*)(Brow + 64);

#pragma unroll
    for (int it = 0; it < 4; ++it) {
      *(uint2*)&A0[dA] = ea0; *(uint2*)&A0[dA + 4] = ea1;
      *(uint4*)&B0[dA] = eb;
      __syncthreads();
      if (it < 3) {
        const int ko = (2 * it + 2) * 64;
        ea0 = ld_dev2(Arow + ko); ea1 = ld_dev2(Arow + ko + 4);
        eb = *(const uint4*)(Brow + ko);
      }
#pragma unroll
      for (int kk = 0; kk < 64; kk += 32) {
        bfx8 av = *(const bfx8*)&A0[(wr * 16 + lr) * LSC2 + kk + lk];
#pragma unroll
        for (int ni = 0; ni < 2; ni++) {
          bfx8 bv = *(const bfx8*)&B0[(wc * 32 + ni * 16 + lr) * LSC2 + kk + lk];
          acc[ni] = __builtin_amdgcn_mfma_f32_16x16x32_bf16(av, bv, acc[ni], 0, 0, 0);
        }
      }
      *(uint2*)&A1[dA] = oa0; *(uint2*)&A1[dA + 4] = oa1;
      *(uint4*)&B1[dA] = ob;
      __syncthreads();
      if (it < 3) {
        const int ko = (2 * it + 3) * 64;
        oa0 = ld_dev2(Arow + ko); oa1 = ld_dev2(Arow + ko + 4);
        ob = *(const uint4*)(Brow + ko);
      }
#pragma unroll
      for (int kk = 0; kk < 64; kk += 32) {
        bfx8 av = *(const bfx8*)&A1[(wr * 16 + lr) * LSC2 + kk + lk];
#pragma unroll
        for (int ni = 0; ni < 2; ni++) {
          bfx8 bv = *(const bfx8*)&B1[(wc * 32 + ni * 16 + lr) * LSC2 + kk + lk];
          acc[ni] = __builtin_amdgcn_mfma_f32_16x16x32_bf16(av, bv, acc[ni], 0, 0, 0);
        }
      }
    }

    float sq[4] = {0.f, 0.f, 0.f, 0.f};
    const int wr2 = w >> 1, wc2 = w & 1;
#pragma unroll
    for (int ni = 0; ni < 2; ni++) {
      const int n = n0g + wc2 * 32 + ni * 16 + lr;
      const float bias_v = b_blk[n];
#pragma unroll
      for (int r = 0; r < 4; r++) {
        const float zv = acc[ni][r] + bias_v;
        st_devf(&zbuf[(size_t)(wr2 * 16 + rq + r) * H3 + n], zv);
        sq[r] += zv * zv;
      }
    }
#pragma unroll
    for (int o = 1; o < 16; o <<= 1) {
#pragma unroll
      for (int r = 0; r < 4; r++) sq[r] += __shfl_xor(sq[r], o);
    }
    if (lr == 0) {
#pragma unroll
      for (int r = 0; r < 4; r++)
        st_devf(&zsq[(size_t)wg * 128 + wc2 * 64 + wr2 * 16 + rq + r], sq[r]);
    }
  }

  gbar(bars + 2, 256);

  // ---------- Phase D: block-rms + gates + deter + out (256 WGs x 512 thr) ----------
  {
    const int b = wg >> 2, s = wg & 3;
    if (tid < 8) {
      float ssq = 0.f;
      const int c0 = tid * 24;
#pragma unroll
      for (int j = 0; j < 24; j++) {
        const size_t base = (size_t)(c0 + j) * 128;
        ssq += ld_devf(&zsq[base + b]) + ld_devf(&zsq[base + 64 + b]);
      }
      sred[tid] = rsqrtf(ssq / (float)CH + EPSf);
    }
    __syncthreads();
    const int d0 = s * 1024 + tid * 2;
    const float* zr = zbuf + (size_t)b * H3;
    float2 z0 = u2f2(ld_dev2(zr + d0));
    float2 z1 = u2f2(ld_dev2(zr + DD + d0));
    float2 z2 = u2f2(ld_dev2(zr + 2 * DD + d0));
    float2 dold = *(const float2*)(dF + (size_t)b * DD + d0);
    const float rsA = sred[d0 / CH];
    const float rsB = sred[(DD + d0) / CH];
    const float rsC = sred[(2 * DD + d0) / CH];
    float z0p[2] = {z0.x, z0.y};
    float z1p[2] = {z1.x, z1.y};
    float z2p[2] = {z2.x, z2.y};
    float dop[2] = {dold.x, dold.y};
    float dn[2];
#pragma unroll
    for (int e = 0; e < 2; e++) {
      const int dd = d0 + e;
      const float a0 = z0p[e] * rsA * sblk[dd];
      const float a1 = z1p[e] * rsB * sblk[DD + dd];
      const float a2 = z2p[e] * rsC * sblk[2 * DD + dd];
      const float reset = 1.f / (1.f + __expf(-a0));
      const float cand = tanhf(reset * a1);
      const float upd = 1.f / (1.f + __expf(-(a2 - 1.f)));
      dn[e] = upd * cand + (1.f - upd) * dop[e];
    }
    *(float2*)(dF + (size_t)b * DD + d0) = make_float2(dn[0], dn[1]);
    *(u32*)(dBout + (size_t)b * DD + d0) = (u32)f2bf(dn[0]) | ((u32)f2bf(dn[1]) << 16);
    *(float2*)(out + ((size_t)b * TT + t) * DD + d0) = make_float2(dn[0], dn[1]);
  }
}

// ---------------- host ----------------

extern "C" void kernel_launch(void* const* d_in, const int* in_sizes, int n_in,
                              void* d_out, int out_size, void* d_ws, size_t ws_size,
                              hipStream_t stream) {
  (void)in_sizes; (void)n_in; (void)out_size; (void)ws_size;
  const float* x         = (const float*)d_in[0];  // [B,T,E]
  const float* deter0    = (const float*)d_in[1];  // [B,D]
  const float* W_in      = (const float*)d_in[2];  // [D+E, D]
  const float* b_in      = (const float*)d_in[3];  // [D]
  const float* scale_in  = (const float*)d_in[4];  // [D]
  const float* W_blk     = (const float*)d_in[5];  // [G, D/G, 3D/G]
  const float* b_blk     = (const float*)d_in[6];  // [3D]
  const float* scale_blk = (const float*)d_in[7];  // [G, 3D/G]
  float* out = (float*)d_out;

  char* ws = (char*)d_ws;
  size_t off = 0;
  auto alloc = [&](size_t bytes) -> void* {
    void* p = ws + off;
    off += (bytes + 255) & ~(size_t)255;
    return p;
  };
  u16*   WT    = (u16*)alloc((size_t)DD * (DD + EE) * 2);       // 50.3 MB
  u16*   WbT   = (u16*)alloc((size_t)GG * CH * (DD / GG) * 2);  // 12.6 MB
  u16*   Xproj = (u16*)alloc((size_t)BB * TT * DD * 2);         // 32 MB (bf16)
  float* dF    = (float*)alloc((size_t)BB * DD * 4);            // 1 MB
  u16*   dB    = (u16*)alloc((size_t)BB * DD * 2);              // 0.5 MB
  int*   bars  = (int*)alloc((size_t)TT * 3 * 4);               // 768 B
  // scratch region: xbf (prepass/P1 only) aliases scan-only buffers
  char* scratch = (char*)alloc((size_t)BB * TT * EE * 2);       // 16.8 MB
  u16*   xbf  = (u16*)scratch;
  float* part = (float*)scratch;                                // 4 MB (4 splits)
  size_t o2 = (size_t)4 * BB * DD * 4;
  u16*   ybf  = (u16*)(scratch + o2);                           // 0.5 MB
  o2 += (size_t)BB * DD * 2;
  float* zbuf = (float*)(scratch + o2);                         // 3 MB
  o2 += (size_t)BB * H3 * 4;
  float* zsq  = (float*)(scratch + o2);                         // 96 KB [192][128]

  // prepass: convert & transpose & zero barrier slots
  k_f2b<<<dim3(2048), dim3(256), 0, stream>>>(x, xbf, BB * TT * EE / 4);
  k_transpose_f2b<<<dim3(DD / 32, (DD + EE) / 32, 1), dim3(256), 0, stream>>>(W_in, WT, DD + EE, DD);
  k_transpose_f2b<<<dim3(CH / 32, (DD / GG) / 32, GG), dim3(256), 0, stream>>>(W_blk, WbT, DD / GG, CH);
  k_initdet<<<dim3(BB * DD / 4 / 256), dim3(256), 0, stream>>>(deter0, dF, dB, BB * DD / 4);
  k_zero<<<dim3(1), dim3(256), 0, stream>>>(bars, TT * 3);

  // P1: Xproj = x @ W2 + b_in -> bf16   (M=4096, K=2048, N=4096)
  k_p1<<<dim3(DD / 128, BB * TT / 128), dim3(256), 0, stream>>>(
      xbf, WT + DD, b_in, Xproj);

  // scan: ONE dispatch per step, 3 internal fence-free barriers
  for (int t = 0; t < TT; t++) {
    kStep<<<dim3(256), dim3(512), 0, stream>>>(
        dB, WT, Xproj, scale_in, WbT, b_blk, scale_blk,
        part, ybf, zbuf, zsq, dF, dB, out, t, bars + 3 * t);
  }
}

// Round 14
// 1763.816 us; speedup vs baseline: 1.5570x; 1.5570x over previous
//
#include <hip/hip_runtime.h>

typedef unsigned short u16;
typedef unsigned int u32;
typedef __bf16 bfx8 __attribute__((ext_vector_type(8)));
typedef float f32x4 __attribute__((ext_vector_type(4)));

constexpr int BB = 64;     // batch
constexpr int TT = 64;     // time
constexpr int EE = 2048;   // x feature
constexpr int DD = 4096;   // deter
constexpr int GG = 8;      // groups
constexpr int H3 = 3 * DD;       // 12288
constexpr int CH = H3 / GG;      // 1536
constexpr float EPSf = 1e-4f;

static __device__ __forceinline__ u16 f2bf(float f) {
  u32 u = __builtin_bit_cast(u32, f);
  u32 r = (u + 0x7fffu + ((u >> 16) & 1u)) >> 16;
  return (u16)r;
}
static __device__ __forceinline__ float bf2f(u16 h) {
  return __builtin_bit_cast(float, (u32)h << 16);
}

// async global->LDS, 16B per lane; LDS dest = wave-uniform base + lane*16
#define GLOAD_LDS16(gp, lp)                                                    \
  __builtin_amdgcn_global_load_lds(                                           \
      (const __attribute__((address_space(1))) void*)(gp),                    \
      (__attribute__((address_space(3))) void*)(lp), 16, 0, 0)

// ---------------- prepass kernels ----------------

__global__ void __launch_bounds__(256) k_f2b(const float* __restrict__ in,
                                             u16* __restrict__ out, int n4) {
  int i = blockIdx.x * 256 + threadIdx.x;
  int stride = gridDim.x * 256;
  for (; i < n4; i += stride) {
    float4 v = ((const float4*)in)[i];
    uint2 o;
    o.x = (u32)f2bf(v.x) | ((u32)f2bf(v.y) << 16);
    o.y = (u32)f2bf(v.z) | ((u32)f2bf(v.w) << 16);
    ((uint2*)out)[i] = o;
  }
}

__global__ void __launch_bounds__(256) k_initdet(const float* __restrict__ d0,
                                                 float* __restrict__ dF,
                                                 u16* __restrict__ dB, int n4) {
  int i = blockIdx.x * 256 + threadIdx.x;
  if (i < n4) {
    float4 v = ((const float4*)d0)[i];
    ((float4*)dF)[i] = v;
    uint2 o;
    o.x = (u32)f2bf(v.x) | ((u32)f2bf(v.y) << 16);
    o.y = (u32)f2bf(v.z) | ((u32)f2bf(v.w) << 16);
    ((uint2*)dB)[i] = o;
  }
}

// in [R][C] f32 -> out [C][R] bf16  (batched over blockIdx.z)
__global__ void __launch_bounds__(256) k_transpose_f2b(const float* __restrict__ in,
                                                       u16* __restrict__ out,
                                                       int R, int C) {
  __shared__ float tile[32][33];
  size_t base = (size_t)blockIdx.z * R * C;
  in += base; out += base;
  int tx = threadIdx.x & 31, ty = threadIdx.x >> 5;
  int r0 = blockIdx.y * 32, c0 = blockIdx.x * 32;
#pragma unroll
  for (int i = 0; i < 4; i++) {
    int rr = ty * 4 + i;
    tile[rr][tx] = in[(size_t)(r0 + rr) * C + (c0 + tx)];
  }
  __syncthreads();
#pragma unroll
  for (int i = 0; i < 4; i++) {
    int cc = ty * 4 + i;
    out[(size_t)(c0 + cc) * R + (r0 + tx)] = f2bf(tile[tx][cc]);
  }
}

// ---------------- P1: Xproj = x @ W2 + b_in -> bf16 ----------------
// m97 structure + T2 swizzle: linear LDS dest (global_load_lds), source col
// pre-swizzled (slot ^= row&7), ds_read slot swizzled identically.
// Content identical -> bit-identical output vs round 11; bank conflicts gone.

__global__ void __launch_bounds__(256) k_p1(const u16* __restrict__ A,  // [4096][2048]
                                            const u16* __restrict__ B,  // [4096][6144] (W2T at col 0)
                                            const float* __restrict__ bias,
                                            u16* __restrict__ C) {      // [4096][4096] bf16
  __shared__ u16 As[128 * 64];   // 16 KB, linear [row][64]
  __shared__ u16 Bs[128 * 64];   // 16 KB
  const int tid = threadIdx.x;
  const int m0 = blockIdx.y * 128, n0 = blockIdx.x * 128;
  const int w = tid >> 6, lane = tid & 63;
  const int wr = w >> 1, wc = w & 1;
  const int lr = lane & 15, lk = (lane >> 4) * 8;
  // staging: chunk = w*4+i (8 rows x 8 slots); lane covers row chunk*8+(l>>3),
  // dest slot l&7; SOURCE col slot = (l&7) ^ (row&7) = (l&7) ^ (l>>3).
  const int lrow = lane >> 3;
  const int lcol = (((lane & 7) ^ (lane >> 3)) << 3);
  const u16* gA[4];
  const u16* gB[4];
  u16* lA[4];
  u16* lB[4];
#pragma unroll
  for (int i = 0; i < 4; i++) {
    const int chunk = w * 4 + i;
    const int row = chunk * 8 + lrow;
    gA[i] = A + (size_t)(m0 + row) * EE + lcol;
    gB[i] = B + (size_t)(n0 + row) * (DD + EE) + lcol;
    lA[i] = &As[chunk * 512];
    lB[i] = &Bs[chunk * 512];
  }

  f32x4 acc[4][4] = {};

  for (int kt = 0; kt < EE; kt += 64) {
#pragma unroll
    for (int i = 0; i < 4; i++) {
      GLOAD_LDS16(gA[i] + kt, lA[i]);
      GLOAD_LDS16(gB[i] + kt, lB[i]);
    }
    __syncthreads();
#pragma unroll
    for (int kk = 0; kk < 64; kk += 32) {
      const int sl = (((kk + lk) >> 3) ^ (lr & 7)) << 3;  // swizzled slot offset
      bfx8 av[4], bv[4];
#pragma unroll
      for (int mi = 0; mi < 4; mi++)
        av[mi] = *(const bfx8*)&As[(wr * 64 + mi * 16 + lr) * 64 + sl];
#pragma unroll
      for (int ni = 0; ni < 4; ni++)
        bv[ni] = *(const bfx8*)&Bs[(wc * 64 + ni * 16 + lr) * 64 + sl];
#pragma unroll
      for (int mi = 0; mi < 4; mi++)
#pragma unroll
        for (int ni = 0; ni < 4; ni++)
          acc[mi][ni] = __builtin_amdgcn_mfma_f32_16x16x32_bf16(av[mi], bv[ni], acc[mi][ni], 0, 0, 0);
    }
    __syncthreads();
  }

  const int rq = (lane >> 4) * 4;
#pragma unroll
  for (int mi = 0; mi < 4; mi++) {
#pragma unroll
    for (int ni = 0; ni < 4; ni++) {
      const int n = n0 + wc * 64 + ni * 16 + lr;
      const float bias_v = bias[n];
#pragma unroll
      for (int r = 0; r < 4; r++) {
        const int m = m0 + wr * 64 + mi * 16 + rq + r;
        C[(size_t)m * DD + n] = f2bf(acc[mi][ni][r] + bias_v);
      }
    }
  }
}

// ---------------- scan kernels ----------------
// kA: part[kc] = dB @ W1[:, kc*1024 .. +1024]
// global_load_lds staging (async DMA), linear [64][128] LDS, dbuf, 1 barrier/iter.
// Source cols pre-swizzled (slot ^= row&15); reads use the same XOR -> 2-way
// bank aliasing (free). MFMA inputs identical to round 11 -> bit-identical.

__global__ void __launch_bounds__(512) kA(const u16* __restrict__ dB,
                                          const u16* __restrict__ WT,
                                          float* __restrict__ part) {
  __shared__ u16 As[2 * 8192];   // 32 KB
  __shared__ u16 Bs[2 * 8192];   // 32 KB
  const int tid = threadIdx.x;
  const int n0 = blockIdx.x * 64;
  const int k0 = blockIdx.y * 1024;
  const int w = tid >> 6, lane = tid & 63;
  const int wr = w >> 1, wc = w & 1;
  const int lr = lane & 15, lk = (lane >> 4) * 8, rq = (lane >> 4) * 4;
  // staging: chunk c = half*512 + w*64 + lane -> row = c>>4, dest slot = lane&15.
  // Source col slot = (lane&15) ^ (row&15).
  const int r0 = w * 4 + (lane >> 4);          // rows 0..31 (half 0)
  const int r1 = r0 + 32;                      // rows 32..63 (half 1)
  const int s0 = (((lane & 15) ^ (r0 & 15)) << 3);
  const int s1 = (((lane & 15) ^ (r1 & 15)) << 3);
  const u16* gA0 = dB + (size_t)r0 * DD + k0 + s0;
  const u16* gA1 = dB + (size_t)r1 * DD + k0 + s1;
  const u16* gB0 = WT + (size_t)(n0 + r0) * (DD + EE) + k0 + s0;
  const u16* gB1 = WT + (size_t)(n0 + r1) * (DD + EE) + k0 + s1;
  u16* dA0 = &As[0] + w * 512;
  u16* dA1 = &As[0] + 4096 + w * 512;
  u16* dB0 = &Bs[0] + w * 512;
  u16* dB1 = &Bs[0] + 4096 + w * 512;

  f32x4 acc[2] = {};
  GLOAD_LDS16(gA0, dA0);
  GLOAD_LDS16(gA1, dA1);
  GLOAD_LDS16(gB0, dB0);
  GLOAD_LDS16(gB1, dB1);
  __syncthreads();

  for (int kt = 0; kt < 8; ++kt) {
    const int p = kt & 1, q = p ^ 1;
    if (kt < 7) {
      const int ko = (kt + 1) * 128;
      GLOAD_LDS16(gA0 + ko, dA0 + q * 8192);
      GLOAD_LDS16(gA1 + ko, dA1 + q * 8192);
      GLOAD_LDS16(gB0 + ko, dB0 + q * 8192);
      GLOAD_LDS16(gB1 + ko, dB1 + q * 8192);
    }
    const u16* ab = &As[p * 8192];
    const u16* bb = &Bs[p * 8192];
#pragma unroll
    for (int kk = 0; kk < 128; kk += 32) {
      const int sl = ((((kk + lk) >> 3)) ^ lr) << 3;   // swizzled slot offset
      bfx8 av = *(const bfx8*)&ab[(wr * 16 + lr) * 128 + sl];
#pragma unroll
      for (int ni = 0; ni < 2; ni++) {
        bfx8 bv = *(const bfx8*)&bb[(wc * 32 + ni * 16 + lr) * 128 + sl];
        acc[ni] = __builtin_amdgcn_mfma_f32_16x16x32_bf16(av, bv, acc[ni], 0, 0, 0);
      }
    }
    __syncthreads();
  }

  float* Pp = part + (size_t)blockIdx.y * BB * DD;
#pragma unroll
  for (int ni = 0; ni < 2; ni++)
#pragma unroll
    for (int r = 0; r < 4; r++)
      Pp[(size_t)(wr * 16 + rq + r) * DD + n0 + wc * 32 + ni * 16 + lr] = acc[ni][r];
}

// kB: y = silu(rms(sum_kc part + Xproj_t) * scale_in) -> bf16   grid 64 x 512 thr
__global__ void __launch_bounds__(512) kB(const float* __restrict__ part,
                                          const u16* __restrict__ Xproj,
                                          const float* __restrict__ scale_in,
                                          u16* __restrict__ ybf, int t) {
  const int b = blockIdx.x, tid = threadIdx.x;
  const int w = tid >> 6, lane = tid & 63;
  __shared__ float sred[8];
  const u16* xp = Xproj + ((size_t)b * TT + t) * DD + tid * 8;
  const float* pb = part + (size_t)b * DD + tid * 8;
  float v[8];
  uint4 x0 = *(const uint4*)(xp);
#pragma unroll
  for (int j = 0; j < 8; j++) v[j] = bf2f(((const u16*)&x0)[j]);
#pragma unroll
  for (int kc = 0; kc < 4; kc++) {
    const float* p = pb + (size_t)kc * BB * DD;
    float4 q0 = *(const float4*)(p);
    float4 q1 = *(const float4*)(p + 4);
    v[0] += q0.x; v[1] += q0.y; v[2] += q0.z; v[3] += q0.w;
    v[4] += q1.x; v[5] += q1.y; v[6] += q1.z; v[7] += q1.w;
  }
  float ss = 0.f;
#pragma unroll
  for (int j = 0; j < 8; j++) ss += v[j] * v[j];
#pragma unroll
  for (int o = 32; o > 0; o >>= 1) ss += __shfl_down(ss, o);
  if (lane == 0) sred[w] = ss;
  __syncthreads();
  float tot = 0.f;
#pragma unroll
  for (int i = 0; i < 8; i++) tot += sred[i];
  const float r = rsqrtf(tot / (float)DD + EPSf);
  const float* sc = scale_in + tid * 8;
  u32 pk[4];
#pragma unroll
  for (int j = 0; j < 4; j++) {
    float a = v[2 * j] * r * sc[2 * j];
    float bq = v[2 * j + 1] * r * sc[2 * j + 1];
    a = a / (1.f + __expf(-a));
    bq = bq / (1.f + __expf(-bq));
    pk[j] = (u32)f2bf(a) | ((u32)f2bf(bq) << 16);
  }
  *(uint4*)(ybf + (size_t)b * DD + tid * 8) = make_uint4(pk[0], pk[1], pk[2], pk[3]);
}

// kC: z = blockdiag(y @ Wblk) + b_blk -> zbuf f32; fused per-row sumsq -> zsq[192][64]
// (round-11 proven body, unchanged)
constexpr int LSC2 = 72;
constexpr int CBUF = 64 * LSC2;

__global__ void __launch_bounds__(256) kC(const u16* __restrict__ ybf,
                                          const u16* __restrict__ WbT,
                                          const float* __restrict__ b_blk,
                                          float* __restrict__ zbuf,
                                          float* __restrict__ zsq) {
  __shared__ u16 As[2 * CBUF];
  __shared__ u16 Bs[2 * CBUF];
  const int tid = threadIdx.x;
  const int wg = blockIdx.x;
  const int n0g = wg * 64;
  const int g = n0g / CH, nl = n0g % CH;
  const int w = tid >> 6, lane = tid & 63;
  const int lr = lane & 15, lk = (lane >> 4) * 8, rq = (lane >> 4) * 4;
  const int srow = tid >> 2, sc = (tid & 3) * 8;
  const u16* Arow = ybf + (size_t)srow * DD + g * (DD / GG) + sc;
  const u16* Brow = WbT + ((size_t)g * CH + nl + srow) * (DD / GG) + sc;
  const int dA = srow * LSC2 + sc;

  f32x4 acc[4] = {};
  uint4 ra0 = *(const uint4*)(Arow);
  uint4 ra1 = *(const uint4*)(Arow + 32);
  uint4 rb0 = *(const uint4*)(Brow);
  uint4 rb1 = *(const uint4*)(Brow + 32);

  for (int kt = 0; kt < 8; ++kt) {
    const int p = kt & 1;
    u16* ab = As + p * CBUF;
    u16* bb = Bs + p * CBUF;
    *(uint4*)&ab[dA] = ra0;
    *(uint4*)&ab[dA + 32] = ra1;
    *(uint4*)&bb[dA] = rb0;
    *(uint4*)&bb[dA + 32] = rb1;
    __syncthreads();
    if (kt < 7) {
      const int ko = (kt + 1) * 64;
      ra0 = *(const uint4*)(Arow + ko);
      ra1 = *(const uint4*)(Arow + ko + 32);
      rb0 = *(const uint4*)(Brow + ko);
      rb1 = *(const uint4*)(Brow + ko + 32);
    }
#pragma unroll
    for (int kk = 0; kk < 64; kk += 32) {
      bfx8 av = *(const bfx8*)&ab[(w * 16 + lr) * LSC2 + kk + lk];
#pragma unroll
      for (int ni = 0; ni < 4; ni++) {
        bfx8 bv = *(const bfx8*)&bb[(ni * 16 + lr) * LSC2 + kk + lk];
        acc[ni] = __builtin_amdgcn_mfma_f32_16x16x32_bf16(av, bv, acc[ni], 0, 0, 0);
      }
    }
  }

  float sq[4] = {0.f, 0.f, 0.f, 0.f};
#pragma unroll
  for (int ni = 0; ni < 4; ni++) {
    const int n = n0g + ni * 16 + lr;
    const float bias_v = b_blk[n];
#pragma unroll
    for (int r = 0; r < 4; r++) {
      const float zv = acc[ni][r] + bias_v;
      zbuf[(size_t)(w * 16 + rq + r) * H3 + n] = zv;
      sq[r] += zv * zv;
    }
  }
#pragma unroll
  for (int o = 1; o < 16; o <<= 1) {
#pragma unroll
    for (int r = 0; r < 4; r++) sq[r] += __shfl_xor(sq[r], o);
  }
  if (lr == 0) {
#pragma unroll
    for (int r = 0; r < 4; r++) zsq[(size_t)wg * 64 + w * 16 + rq + r] = sq[r];
  }
}

// kD: block-rms + gates + deter update + out write   grid 256 (= 64 b x 4 col-slices)
__global__ void __launch_bounds__(256) kD(const float* __restrict__ zbuf,
                                          const float* __restrict__ zsq,
                                          const float* __restrict__ sblk,
                                          float* __restrict__ dF,
                                          u16* __restrict__ dB,
                                          float* __restrict__ out, int t) {
  const int wg = blockIdx.x, tid = threadIdx.x;
  const int b = wg >> 2, s = wg & 3;
  __shared__ float sred[8];
  if (tid < 8) {
    float ssq = 0.f;
    const int j0 = tid * 24;
#pragma unroll
    for (int j = 0; j < 24; j++) ssq += zsq[(size_t)(j0 + j) * 64 + b];
    sred[tid] = rsqrtf(ssq / (float)CH + EPSf);
  }
  __syncthreads();
  const int d0 = s * 1024 + tid * 4;
  const float* zr = zbuf + (size_t)b * H3;
  float4 z0 = *(const float4*)(zr + d0);
  float4 z1 = *(const float4*)(zr + DD + d0);
  float4 z2 = *(const float4*)(zr + 2 * DD + d0);
  float4 dold = *(const float4*)(dF + (size_t)b * DD + d0);
  const float rsA = sred[d0 / CH];
  const float rsB = sred[(DD + d0) / CH];
  const float rsC = sred[(2 * DD + d0) / CH];
  float dn[4];
  const float* z0p = (const float*)&z0;
  const float* z1p = (const float*)&z1;
  const float* z2p = (const float*)&z2;
  const float* dop = (const float*)&dold;
#pragma unroll
  for (int e = 0; e < 4; e++) {
    const int dd = d0 + e;
    const float a0 = z0p[e] * rsA * sblk[dd];
    const float a1 = z1p[e] * rsB * sblk[DD + dd];
    const float a2 = z2p[e] * rsC * sblk[2 * DD + dd];
    const float reset = 1.f / (1.f + __expf(-a0));
    const float cand = tanhf(reset * a1);
    const float upd = 1.f / (1.f + __expf(-(a2 - 1.f)));
    dn[e] = upd * cand + (1.f - upd) * dop[e];
  }
  *(float4*)(dF + (size_t)b * DD + d0) = make_float4(dn[0], dn[1], dn[2], dn[3]);
  uint2 o;
  o.x = (u32)f2bf(dn[0]) | ((u32)f2bf(dn[1]) << 16);
  o.y = (u32)f2bf(dn[2]) | ((u32)f2bf(dn[3]) << 16);
  *(uint2*)(dB + (size_t)b * DD + d0) = o;
  *(float4*)(out + ((size_t)b * TT + t) * DD + d0) = make_float4(dn[0], dn[1], dn[2], dn[3]);
}

// ---------------- host ----------------

extern "C" void kernel_launch(void* const* d_in, const int* in_sizes, int n_in,
                              void* d_out, int out_size, void* d_ws, size_t ws_size,
                              hipStream_t stream) {
  (void)in_sizes; (void)n_in; (void)out_size; (void)ws_size;
  const float* x         = (const float*)d_in[0];  // [B,T,E]
  const float* deter0    = (const float*)d_in[1];  // [B,D]
  const float* W_in      = (const float*)d_in[2];  // [D+E, D]
  const float* b_in      = (const float*)d_in[3];  // [D]
  const float* scale_in  = (const float*)d_in[4];  // [D]
  const float* W_blk     = (const float*)d_in[5];  // [G, D/G, 3D/G]
  const float* b_blk     = (const float*)d_in[6];  // [3D]
  const float* scale_blk = (const float*)d_in[7];  // [G, 3D/G]
  float* out = (float*)d_out;

  char* ws = (char*)d_ws;
  size_t off = 0;
  auto alloc = [&](size_t bytes) -> void* {
    void* p = ws + off;
    off += (bytes + 255) & ~(size_t)255;
    return p;
  };
  u16*   WT    = (u16*)alloc((size_t)DD * (DD + EE) * 2);       // 50.3 MB
  u16*   WbT   = (u16*)alloc((size_t)GG * CH * (DD / GG) * 2);  // 12.6 MB
  u16*   Xproj = (u16*)alloc((size_t)BB * TT * DD * 2);         // 32 MB (bf16)
  float* dF    = (float*)alloc((size_t)BB * DD * 4);            // 1 MB
  u16*   dB    = (u16*)alloc((size_t)BB * DD * 2);              // 0.5 MB
  // scratch region: xbf (prepass/P1 only) aliases scan-only buffers
  char* scratch = (char*)alloc((size_t)BB * TT * EE * 2);       // 16.8 MB
  u16*   xbf  = (u16*)scratch;
  float* part = (float*)scratch;                                // 4 MB (4 splits)
  size_t o2 = (size_t)4 * BB * DD * 4;
  u16*   ybf  = (u16*)(scratch + o2);                           // 0.5 MB
  o2 += (size_t)BB * DD * 2;
  float* zbuf = (float*)(scratch + o2);                         // 3 MB
  o2 += (size_t)BB * H3 * 4;
  float* zsq  = (float*)(scratch + o2);                         // 48 KB

  // prepass: convert & transpose
  k_f2b<<<dim3(2048), dim3(256), 0, stream>>>(x, xbf, BB * TT * EE / 4);
  k_transpose_f2b<<<dim3(DD / 32, (DD + EE) / 32, 1), dim3(256), 0, stream>>>(W_in, WT, DD + EE, DD);
  k_transpose_f2b<<<dim3(CH / 32, (DD / GG) / 32, GG), dim3(256), 0, stream>>>(W_blk, WbT, DD / GG, CH);
  k_initdet<<<dim3(BB * DD / 4 / 256), dim3(256), 0, stream>>>(deter0, dF, dB, BB * DD / 4);

  // P1: Xproj = x @ W2 + b_in -> bf16   (M=4096, K=2048, N=4096)
  k_p1<<<dim3(DD / 128, BB * TT / 128), dim3(256), 0, stream>>>(
      xbf, WT + DD, b_in, Xproj);

  // scan: 4 dispatches/step (proven fastest sync structure)
  for (int t = 0; t < TT; t++) {
    kA<<<dim3(64, 4), dim3(512), 0, stream>>>(dB, WT, part);
    kB<<<dim3(BB), dim3(512), 0, stream>>>(part, Xproj, scale_in, ybf, t);
    kC<<<dim3(192), dim3(256), 0, stream>>>(ybf, WbT, b_blk, zbuf, zsq);
    kD<<<dim3(256), dim3(256), 0, stream>>>(zbuf, zsq, scale_blk, dF, dB, out, t);
  }
}